// Round 1
// baseline (372.140 us; speedup 1.0000x reference)
//
#include <hip/hip_runtime.h>
#include <hip/hip_bf16.h>

#define F_DIM 128

// ---------------- CSR build ----------------

__global__ void count_kernel(const int* __restrict__ dst, int* __restrict__ deg, int E_) {
    int i = blockIdx.x * blockDim.x + threadIdx.x;
    if (i < E_) atomicAdd(&deg[dst[i]], 1);
}

__global__ void scan_blocksums_kernel(const int* __restrict__ deg, int* __restrict__ bsum, int N_) {
    __shared__ int s[256];
    int i = blockIdx.x * 256 + threadIdx.x;
    s[threadIdx.x] = (i < N_) ? deg[i] : 0;
    __syncthreads();
    for (int off = 128; off; off >>= 1) {
        if (threadIdx.x < off) s[threadIdx.x] += s[threadIdx.x + off];
        __syncthreads();
    }
    if (threadIdx.x == 0) bsum[blockIdx.x] = s[0];
}

__global__ void scan_bs_kernel(const int* __restrict__ bsum, int* __restrict__ bsx, int NB) {
    __shared__ int s[256];
    int t = threadIdx.x;
    int orig = (t < NB) ? bsum[t] : 0;
    s[t] = orig;
    __syncthreads();
    for (int off = 1; off < 256; off <<= 1) {
        int v = (t >= off) ? s[t - off] : 0;
        __syncthreads();
        s[t] += v;
        __syncthreads();
    }
    if (t < NB) bsx[t] = s[t] - orig;   // exclusive
}

__global__ void scan_final_kernel(const int* __restrict__ deg, const int* __restrict__ bsx,
                                  int* __restrict__ row_ptr, int* __restrict__ rfill, int N_) {
    __shared__ int s[256];
    int t = threadIdx.x;
    int i = blockIdx.x * 256 + t;
    int orig = (i < N_) ? deg[i] : 0;
    s[t] = orig;
    __syncthreads();
    for (int off = 1; off < 256; off <<= 1) {
        int v = (t >= off) ? s[t - off] : 0;
        __syncthreads();
        s[t] += v;
        __syncthreads();
    }
    int excl = s[t] - orig + bsx[blockIdx.x];
    if (i < N_) { row_ptr[i] = excl; rfill[i] = excl; }
    if (i == N_ - 1) row_ptr[N_] = excl + orig;  // = E
}

__global__ void dinv_kernel(const int* __restrict__ deg, float* __restrict__ dinv, int N_) {
    int i = blockIdx.x * blockDim.x + threadIdx.x;
    if (i < N_) dinv[i] = 1.0f / sqrtf((float)(deg[i] + 1));  // +1 self-loop; always > 0
}

__global__ void fill_kernel(const int* __restrict__ src, const int* __restrict__ dst,
                            int* __restrict__ cur, int* __restrict__ col_src, int E_) {
    int i = blockIdx.x * blockDim.x + threadIdx.x;
    if (i < E_) {
        int p = atomicAdd(&cur[dst[i]], 1);
        col_src[p] = src[i];
    }
}

// ---------------- GEMM: out[r][c] = dinv[r] * sum_k in[r][k] * W[k][c] ----------------
// 64x64 block tile, full K=128 in LDS (exactly 64KB), 4x4 register tile.
// h-tile stored [r][k] with XOR swizzle on k so column-slice b128 reads are ~conflict-free.

__global__ __launch_bounds__(256) void gemm_scale_kernel(
    const float* __restrict__ in, const float* __restrict__ W,
    const float* __restrict__ dinv, float* __restrict__ out, int N_)
{
    __shared__ float hl[64][F_DIM];   // 32 KB, k-index XOR-swizzled per row
    __shared__ float Wl[F_DIM][64];   // 32 KB
    const int tid = threadIdx.x;
    const int brow = (blockIdx.x >> 1) * 64;
    const int bcol = (blockIdx.x & 1) * 64;

    // stage input tile: 64 rows x 128 k = 2048 float4 chunks, 8 per thread (coalesced)
    #pragma unroll
    for (int i = 0; i < 8; ++i) {
        int chunk = tid + i * 256;
        int r = chunk >> 5;        // 0..63
        int k4 = chunk & 31;       // 0..31
        int row = brow + r;
        float4 g = make_float4(0.f, 0.f, 0.f, 0.f);
        if (row < N_) g = *reinterpret_cast<const float4*>(&in[(size_t)row * F_DIM + k4 * 4]);
        int sw = (r & 7) << 2;
        *reinterpret_cast<float4*>(&hl[r][(k4 * 4) ^ sw]) = g;
    }
    // stage W tile (coalesced, linear)
    #pragma unroll
    for (int i = 0; i < 8; ++i) {
        int chunk = tid + i * 256;
        int k = chunk >> 4;        // 0..127
        int c4 = chunk & 15;       // 0..15
        *reinterpret_cast<float4*>(&Wl[k][c4 * 4]) =
            *reinterpret_cast<const float4*>(&W[(size_t)k * F_DIM + bcol + c4 * 4]);
    }
    __syncthreads();

    const int cg = tid & 15;       // col group: cols cg*4..+3
    const int rg = tid >> 4;       // row group: rows rg*4..+3
    const int r0 = rg * 4;
    float acc[4][4] = {};

    #pragma unroll 4
    for (int kk = 0; kk < 32; ++kk) {
        float4 a[4], b[4];
        #pragma unroll
        for (int i = 0; i < 4; ++i) {
            int r = r0 + i;
            int sw = (r & 7) << 2;
            a[i] = *reinterpret_cast<const float4*>(&hl[r][(kk * 4) ^ sw]);
        }
        #pragma unroll
        for (int j = 0; j < 4; ++j)
            b[j] = *reinterpret_cast<const float4*>(&Wl[kk * 4 + j][cg * 4]);
        #pragma unroll
        for (int i = 0; i < 4; ++i) {
            float4 ai = a[i];
            acc[i][0] += ai.x * b[0].x + ai.y * b[1].x + ai.z * b[2].x + ai.w * b[3].x;
            acc[i][1] += ai.x * b[0].y + ai.y * b[1].y + ai.z * b[2].y + ai.w * b[3].y;
            acc[i][2] += ai.x * b[0].z + ai.y * b[1].z + ai.z * b[2].z + ai.w * b[3].z;
            acc[i][3] += ai.x * b[0].w + ai.y * b[1].w + ai.z * b[2].w + ai.w * b[3].w;
        }
    }

    #pragma unroll
    for (int i = 0; i < 4; ++i) {
        int row = brow + r0 + i;
        if (row < N_) {
            float s = dinv[row];
            float4 o = make_float4(s * acc[i][0], s * acc[i][1], s * acc[i][2], s * acc[i][3]);
            *reinterpret_cast<float4*>(&out[(size_t)row * F_DIM + bcol + cg * 4]) = o;
        }
    }
}

// ---------------- Gather-aggregate + bias + relu ----------------
// One wave per node (4 nodes/block). acc = m[v] (self loop) + sum_{in-edges} m[src];
// h_out = relu(dinv[v]*acc + b).

__global__ __launch_bounds__(256) void gather_kernel(
    const float* __restrict__ Mbuf, const int* __restrict__ row_ptr,
    const int* __restrict__ col_src, const float* __restrict__ dinv,
    const float* __restrict__ bias, float* __restrict__ Hout, int N_)
{
    int v = blockIdx.x * 4 + (threadIdx.x >> 6);
    if (v >= N_) return;
    int lane = threadIdx.x & 63;
    const float2* M2 = reinterpret_cast<const float2*>(Mbuf);
    float2 acc = M2[(size_t)v * 64 + lane];   // self loop contribution
    int lo = row_ptr[v], hi = row_ptr[v + 1];
    int e = lo;
    for (; e + 4 <= hi; e += 4) {
        int s0 = col_src[e + 0], s1 = col_src[e + 1], s2 = col_src[e + 2], s3 = col_src[e + 3];
        float2 m0 = M2[(size_t)s0 * 64 + lane];
        float2 m1 = M2[(size_t)s1 * 64 + lane];
        float2 m2 = M2[(size_t)s2 * 64 + lane];
        float2 m3 = M2[(size_t)s3 * 64 + lane];
        acc.x += (m0.x + m1.x) + (m2.x + m3.x);
        acc.y += (m0.y + m1.y) + (m2.y + m3.y);
    }
    for (; e < hi; ++e) {
        int s = col_src[e];
        float2 m = M2[(size_t)s * 64 + lane];
        acc.x += m.x; acc.y += m.y;
    }
    float dv = dinv[v];
    float2 bb = reinterpret_cast<const float2*>(bias)[lane];
    float2 o;
    o.x = fmaxf(dv * acc.x + bb.x, 0.0f);
    o.y = fmaxf(dv * acc.y + bb.y, 0.0f);
    reinterpret_cast<float2*>(Hout)[(size_t)v * 64 + lane] = o;
}

// ---------------- Mean-pool per graph + final linear ----------------

__device__ __forceinline__ int lower_bound_i(const int* __restrict__ a, int n, int key) {
    int lo = 0, hi = n;
    while (lo < hi) {
        int mid = (lo + hi) >> 1;
        if (a[mid] < key) lo = mid + 1; else hi = mid;
    }
    return lo;
}

__global__ __launch_bounds__(256) void pool_kernel(
    const float* __restrict__ H, const int* __restrict__ batch,
    const float* __restrict__ lin_w, const float* __restrict__ lin_b,
    float* __restrict__ out, int N_)
{
    int g = blockIdx.x;
    int lo = lower_bound_i(batch, N_, g);
    int hi = lower_bound_i(batch, N_, g + 1);
    int col = threadIdx.x & 127;
    int half = threadIdx.x >> 7;
    float acc = 0.f;
    for (int n = lo + half; n < hi; n += 2) acc += H[(size_t)n * F_DIM + col];
    __shared__ float s[256];
    s[threadIdx.x] = acc;
    __syncthreads();
    if (threadIdx.x < 128) {
        float tot = s[threadIdx.x] + s[threadIdx.x + 128];
        float cnt = (float)(hi - lo);
        float pooled = tot / fmaxf(cnt, 1.0f);
        s[threadIdx.x] = pooled * lin_w[threadIdx.x];
    }
    __syncthreads();
    if (threadIdx.x < 64) {
        float v = s[threadIdx.x] + s[threadIdx.x + 64];
        for (int off = 32; off; off >>= 1) v += __shfl_down(v, off);
        if (threadIdx.x == 0) out[g] = v + lin_b[0];
    }
}

// ---------------- Launch ----------------

extern "C" void kernel_launch(void* const* d_in, const int* in_sizes, int n_in,
                              void* d_out, int out_size, void* d_ws, size_t ws_size,
                              hipStream_t stream) {
    const float* x     = (const float*)d_in[0];
    const int*   ei    = (const int*)d_in[1];
    const int*   batch = (const int*)d_in[2];
    const float* W0    = (const float*)d_in[3];
    const float* b0    = (const float*)d_in[4];
    const float* W1    = (const float*)d_in[5];
    const float* b1    = (const float*)d_in[6];
    const float* W2    = (const float*)d_in[7];
    const float* b2    = (const float*)d_in[8];
    const float* lin_w = (const float*)d_in[9];
    const float* lin_b = (const float*)d_in[10];

    const int N_ = in_sizes[2];
    const int E_ = in_sizes[1] / 2;
    const int G_ = out_size;
    const int* esrc = ei;
    const int* edst = ei + E_;

    // workspace layout
    float* Mbuf  = reinterpret_cast<float*>(d_ws);
    float* Hbuf  = Mbuf + (size_t)N_ * F_DIM;
    float* dinvp = Hbuf + (size_t)N_ * F_DIM;
    int*   deg   = reinterpret_cast<int*>(dinvp + N_);
    int*   row_ptr = deg + N_;
    int*   rfill   = row_ptr + N_ + 4;
    int*   col_src = rfill + N_;
    int*   bsum    = col_src + E_;
    const int NB = (N_ + 255) / 256;   // 157 for N=40000, must be <= 256
    int*   bsx     = bsum + NB;

    hipMemsetAsync(deg, 0, (size_t)N_ * sizeof(int), stream);

    int eb = (E_ + 255) / 256;
    count_kernel<<<eb, 256, 0, stream>>>(edst, deg, E_);
    scan_blocksums_kernel<<<NB, 256, 0, stream>>>(deg, bsum, N_);
    scan_bs_kernel<<<1, 256, 0, stream>>>(bsum, bsx, NB);
    scan_final_kernel<<<NB, 256, 0, stream>>>(deg, bsx, row_ptr, rfill, N_);
    dinv_kernel<<<(N_ + 255) / 256, 256, 0, stream>>>(deg, dinvp, N_);
    fill_kernel<<<eb, 256, 0, stream>>>(esrc, edst, rfill, col_src, E_);

    const int gemm_grid = ((N_ + 63) / 64) * 2;
    const int gat_grid  = (N_ + 3) / 4;

    const float* cur_in = x;
    const float* Ws[3] = {W0, W1, W2};
    const float* bias[3] = {b0, b1, b2};
    for (int l = 0; l < 3; ++l) {
        gemm_scale_kernel<<<gemm_grid, 256, 0, stream>>>(cur_in, Ws[l], dinvp, Mbuf, N_);
        gather_kernel<<<gat_grid, 256, 0, stream>>>(Mbuf, row_ptr, col_src, dinvp, bias[l], Hbuf, N_);
        cur_in = Hbuf;
    }

    pool_kernel<<<G_, 256, 0, stream>>>(Hbuf, batch, lin_w, lin_b, (float*)d_out, N_);
}

// Round 2
// 314.141 us; speedup vs baseline: 1.1846x; 1.1846x over previous
//
#include <hip/hip_runtime.h>
#include <hip/hip_bf16.h>

#define F_DIM 128
#define POOL_SEG 16

// ---------------- CSR build ----------------

__global__ void count_kernel(const int* __restrict__ dst, int* __restrict__ deg, int E_) {
    int i = blockIdx.x * blockDim.x + threadIdx.x;
    if (i < E_) atomicAdd(&deg[dst[i]], 1);
}

__global__ void scan_blocksums_kernel(const int* __restrict__ deg, int* __restrict__ bsum, int N_) {
    __shared__ int s[256];
    int i = blockIdx.x * 256 + threadIdx.x;
    s[threadIdx.x] = (i < N_) ? deg[i] : 0;
    __syncthreads();
    for (int off = 128; off; off >>= 1) {
        if (threadIdx.x < off) s[threadIdx.x] += s[threadIdx.x + off];
        __syncthreads();
    }
    if (threadIdx.x == 0) bsum[blockIdx.x] = s[0];
}

__global__ void scan_bs_kernel(const int* __restrict__ bsum, int* __restrict__ bsx, int NB) {
    __shared__ int s[256];
    int t = threadIdx.x;
    int orig = (t < NB) ? bsum[t] : 0;
    s[t] = orig;
    __syncthreads();
    for (int off = 1; off < 256; off <<= 1) {
        int v = (t >= off) ? s[t - off] : 0;
        __syncthreads();
        s[t] += v;
        __syncthreads();
    }
    if (t < NB) bsx[t] = s[t] - orig;   // exclusive
}

__global__ void scan_final_kernel(const int* __restrict__ deg, const int* __restrict__ bsx,
                                  int* __restrict__ row_ptr, int* __restrict__ rfill, int N_) {
    __shared__ int s[256];
    int t = threadIdx.x;
    int i = blockIdx.x * 256 + t;
    int orig = (i < N_) ? deg[i] : 0;
    s[t] = orig;
    __syncthreads();
    for (int off = 1; off < 256; off <<= 1) {
        int v = (t >= off) ? s[t - off] : 0;
        __syncthreads();
        s[t] += v;
        __syncthreads();
    }
    int excl = s[t] - orig + bsx[blockIdx.x];
    if (i < N_) { row_ptr[i] = excl; rfill[i] = excl; }
    if (i == N_ - 1) row_ptr[N_] = excl + orig;  // = E
}

__global__ void dinv_kernel(const int* __restrict__ deg, float* __restrict__ dinv, int N_) {
    int i = blockIdx.x * blockDim.x + threadIdx.x;
    if (i < N_) dinv[i] = 1.0f / sqrtf((float)(deg[i] + 1));  // +1 self-loop; always > 0
}

__global__ void fill_kernel(const int* __restrict__ src, const int* __restrict__ dst,
                            int* __restrict__ cur, int* __restrict__ col_src, int E_) {
    int i = blockIdx.x * blockDim.x + threadIdx.x;
    if (i < E_) {
        int p = atomicAdd(&cur[dst[i]], 1);
        col_src[p] = src[i];
    }
}

// ---------------- GEMM: out[r][c] = dinv[r] * sum_k in[r][k] * W[k][c] ----------------

__global__ __launch_bounds__(256) void gemm_scale_kernel(
    const float* __restrict__ in, const float* __restrict__ W,
    const float* __restrict__ dinv, float* __restrict__ out, int N_)
{
    __shared__ float hl[64][F_DIM];   // 32 KB, k-index XOR-swizzled per row
    __shared__ float Wl[F_DIM][64];   // 32 KB
    const int tid = threadIdx.x;
    const int brow = (blockIdx.x >> 1) * 64;
    const int bcol = (blockIdx.x & 1) * 64;

    #pragma unroll
    for (int i = 0; i < 8; ++i) {
        int chunk = tid + i * 256;
        int r = chunk >> 5;        // 0..63
        int k4 = chunk & 31;       // 0..31
        int row = brow + r;
        float4 g = make_float4(0.f, 0.f, 0.f, 0.f);
        if (row < N_) g = *reinterpret_cast<const float4*>(&in[(size_t)row * F_DIM + k4 * 4]);
        int sw = (r & 7) << 2;
        *reinterpret_cast<float4*>(&hl[r][(k4 * 4) ^ sw]) = g;
    }
    #pragma unroll
    for (int i = 0; i < 8; ++i) {
        int chunk = tid + i * 256;
        int k = chunk >> 4;        // 0..127
        int c4 = chunk & 15;       // 0..15
        *reinterpret_cast<float4*>(&Wl[k][c4 * 4]) =
            *reinterpret_cast<const float4*>(&W[(size_t)k * F_DIM + bcol + c4 * 4]);
    }
    __syncthreads();

    const int cg = tid & 15;
    const int rg = tid >> 4;
    const int r0 = rg * 4;
    float acc[4][4] = {};

    #pragma unroll 4
    for (int kk = 0; kk < 32; ++kk) {
        float4 a[4], b[4];
        #pragma unroll
        for (int i = 0; i < 4; ++i) {
            int r = r0 + i;
            int sw = (r & 7) << 2;
            a[i] = *reinterpret_cast<const float4*>(&hl[r][(kk * 4) ^ sw]);
        }
        #pragma unroll
        for (int j = 0; j < 4; ++j)
            b[j] = *reinterpret_cast<const float4*>(&Wl[kk * 4 + j][cg * 4]);
        #pragma unroll
        for (int i = 0; i < 4; ++i) {
            float4 ai = a[i];
            acc[i][0] += ai.x * b[0].x + ai.y * b[1].x + ai.z * b[2].x + ai.w * b[3].x;
            acc[i][1] += ai.x * b[0].y + ai.y * b[1].y + ai.z * b[2].y + ai.w * b[3].y;
            acc[i][2] += ai.x * b[0].z + ai.y * b[1].z + ai.z * b[2].z + ai.w * b[3].z;
            acc[i][3] += ai.x * b[0].w + ai.y * b[1].w + ai.z * b[2].w + ai.w * b[3].w;
        }
    }

    #pragma unroll
    for (int i = 0; i < 4; ++i) {
        int row = brow + r0 + i;
        if (row < N_) {
            float s = dinv[row];
            float4 o = make_float4(s * acc[i][0], s * acc[i][1], s * acc[i][2], s * acc[i][3]);
            *reinterpret_cast<float4*>(&out[(size_t)row * F_DIM + bcol + cg * 4]) = o;
        }
    }
}

// ---------------- Gather-aggregate + bias + relu ----------------

__global__ __launch_bounds__(256) void gather_kernel(
    const float* __restrict__ Mbuf, const int* __restrict__ row_ptr,
    const int* __restrict__ col_src, const float* __restrict__ dinv,
    const float* __restrict__ bias, float* __restrict__ Hout, int N_)
{
    int v = blockIdx.x * 4 + (threadIdx.x >> 6);
    if (v >= N_) return;
    int lane = threadIdx.x & 63;
    const float2* M2 = reinterpret_cast<const float2*>(Mbuf);
    float2 acc = M2[(size_t)v * 64 + lane];   // self loop contribution
    int lo = row_ptr[v], hi = row_ptr[v + 1];
    int e = lo;
    for (; e + 4 <= hi; e += 4) {
        int s0 = col_src[e + 0], s1 = col_src[e + 1], s2 = col_src[e + 2], s3 = col_src[e + 3];
        float2 m0 = M2[(size_t)s0 * 64 + lane];
        float2 m1 = M2[(size_t)s1 * 64 + lane];
        float2 m2 = M2[(size_t)s2 * 64 + lane];
        float2 m3 = M2[(size_t)s3 * 64 + lane];
        acc.x += (m0.x + m1.x) + (m2.x + m3.x);
        acc.y += (m0.y + m1.y) + (m2.y + m3.y);
    }
    for (; e < hi; ++e) {
        int s = col_src[e];
        float2 m = M2[(size_t)s * 64 + lane];
        acc.x += m.x; acc.y += m.y;
    }
    float dv = dinv[v];
    float2 bb = reinterpret_cast<const float2*>(bias)[lane];
    float2 o;
    o.x = fmaxf(dv * acc.x + bb.x, 0.0f);
    o.y = fmaxf(dv * acc.y + bb.y, 0.0f);
    reinterpret_cast<float2*>(Hout)[(size_t)v * 64 + lane] = o;
}

// ---------------- Mean-pool per graph + final linear (two-stage, deterministic) ----------------

__device__ __forceinline__ int lower_bound_i(const int* __restrict__ a, int n, int key) {
    int lo = 0, hi = n;
    while (lo < hi) {
        int mid = (lo + hi) >> 1;
        if (a[mid] < key) lo = mid + 1; else hi = mid;
    }
    return lo;
}

// stage 1: grid = G*POOL_SEG blocks, 128 threads (one column each).
__global__ __launch_bounds__(128) void pool_part_kernel(
    const float* __restrict__ H, const int* __restrict__ batch,
    float* __restrict__ partial, int N_)
{
    int g = blockIdx.x / POOL_SEG;
    int s = blockIdx.x % POOL_SEG;
    int lo = lower_bound_i(batch, N_, g);
    int hi = lower_bound_i(batch, N_, g + 1);
    int len = hi - lo;
    int chunk = (len + POOL_SEG - 1) / POOL_SEG;
    int a = lo + s * chunk;
    int b = min(a + chunk, hi);
    int col = threadIdx.x;
    float acc = 0.f;
    for (int n = a; n < b; ++n) acc += H[(size_t)n * F_DIM + col];
    partial[((size_t)g * POOL_SEG + s) * F_DIM + col] = acc;
}

// stage 2: grid = G blocks, 128 threads.
__global__ __launch_bounds__(128) void pool_final_kernel(
    const float* __restrict__ partial, const int* __restrict__ batch,
    const float* __restrict__ lin_w, const float* __restrict__ lin_b,
    float* __restrict__ out, int N_)
{
    int g = blockIdx.x;
    int col = threadIdx.x;
    float acc = 0.f;
    #pragma unroll
    for (int s = 0; s < POOL_SEG; ++s)
        acc += partial[((size_t)g * POOL_SEG + s) * F_DIM + col];
    int lo = lower_bound_i(batch, N_, g);
    int hi = lower_bound_i(batch, N_, g + 1);
    float pooled = acc / fmaxf((float)(hi - lo), 1.0f);
    float v = pooled * lin_w[col];
    __shared__ float sm[128];
    sm[col] = v;
    __syncthreads();
    if (col < 64) {
        float t = sm[col] + sm[col + 64];
        for (int off = 32; off; off >>= 1) t += __shfl_down(t, off);
        if (col == 0) out[g] = t + lin_b[0];
    }
}

// ---------------- Launch ----------------

extern "C" void kernel_launch(void* const* d_in, const int* in_sizes, int n_in,
                              void* d_out, int out_size, void* d_ws, size_t ws_size,
                              hipStream_t stream) {
    const float* x     = (const float*)d_in[0];
    const int*   ei    = (const int*)d_in[1];
    const int*   batch = (const int*)d_in[2];
    const float* W0    = (const float*)d_in[3];
    const float* b0    = (const float*)d_in[4];
    const float* W1    = (const float*)d_in[5];
    const float* b1    = (const float*)d_in[6];
    const float* W2    = (const float*)d_in[7];
    const float* b2    = (const float*)d_in[8];
    const float* lin_w = (const float*)d_in[9];
    const float* lin_b = (const float*)d_in[10];

    const int N_ = in_sizes[2];
    const int E_ = in_sizes[1] / 2;
    const int G_ = out_size;
    const int* esrc = ei;
    const int* edst = ei + E_;

    // workspace layout
    float* Mbuf  = reinterpret_cast<float*>(d_ws);
    float* Hbuf  = Mbuf + (size_t)N_ * F_DIM;
    float* dinvp = Hbuf + (size_t)N_ * F_DIM;
    int*   deg   = reinterpret_cast<int*>(dinvp + N_);
    int*   row_ptr = deg + N_;
    int*   rfill   = row_ptr + N_ + 4;
    int*   col_src = rfill + N_;
    int*   bsum    = col_src + E_;
    const int NB = (N_ + 255) / 256;
    int*   bsx     = bsum + NB;
    float* partial = Mbuf;   // alias: Mbuf is dead during pooling

    hipMemsetAsync(deg, 0, (size_t)N_ * sizeof(int), stream);

    int eb = (E_ + 255) / 256;
    count_kernel<<<eb, 256, 0, stream>>>(edst, deg, E_);
    scan_blocksums_kernel<<<NB, 256, 0, stream>>>(deg, bsum, N_);
    scan_bs_kernel<<<1, 256, 0, stream>>>(bsum, bsx, NB);
    scan_final_kernel<<<NB, 256, 0, stream>>>(deg, bsx, row_ptr, rfill, N_);
    dinv_kernel<<<(N_ + 255) / 256, 256, 0, stream>>>(deg, dinvp, N_);
    fill_kernel<<<eb, 256, 0, stream>>>(esrc, edst, rfill, col_src, E_);

    const int gemm_grid = ((N_ + 63) / 64) * 2;
    const int gat_grid  = (N_ + 3) / 4;

    const float* cur_in = x;
    const float* Ws[3] = {W0, W1, W2};
    const float* bias[3] = {b0, b1, b2};
    for (int l = 0; l < 3; ++l) {
        gemm_scale_kernel<<<gemm_grid, 256, 0, stream>>>(cur_in, Ws[l], dinvp, Mbuf, N_);
        gather_kernel<<<gat_grid, 256, 0, stream>>>(Mbuf, row_ptr, col_src, dinvp, bias[l], Hbuf, N_);
        cur_in = Hbuf;
    }

    pool_part_kernel<<<G_ * POOL_SEG, 128, 0, stream>>>(Hbuf, batch, partial, N_);
    pool_final_kernel<<<G_, 128, 0, stream>>>(partial, batch, lin_w, lin_b, (float*)d_out, N_);
}

// Round 3
// 277.939 us; speedup vs baseline: 1.3389x; 1.1303x over previous
//
#include <hip/hip_runtime.h>
#include <hip/hip_bf16.h>

#define F_DIM 128
#define POOL_SEG 16

// ---------------- CSR build ----------------

__global__ void count_kernel(const int* __restrict__ dst, int* __restrict__ deg, int E_) {
    int i = blockIdx.x * blockDim.x + threadIdx.x;
    if (i < E_) atomicAdd(&deg[dst[i]], 1);
}

__global__ void scan_blocksums_kernel(const int* __restrict__ deg, int* __restrict__ bsum, int N_) {
    __shared__ int s[256];
    int i = blockIdx.x * 256 + threadIdx.x;
    s[threadIdx.x] = (i < N_) ? deg[i] : 0;
    __syncthreads();
    for (int off = 128; off; off >>= 1) {
        if (threadIdx.x < off) s[threadIdx.x] += s[threadIdx.x + off];
        __syncthreads();
    }
    if (threadIdx.x == 0) bsum[blockIdx.x] = s[0];
}

__global__ void scan_bs_kernel(const int* __restrict__ bsum, int* __restrict__ bsx, int NB) {
    __shared__ int s[256];
    int t = threadIdx.x;
    int orig = (t < NB) ? bsum[t] : 0;
    s[t] = orig;
    __syncthreads();
    for (int off = 1; off < 256; off <<= 1) {
        int v = (t >= off) ? s[t - off] : 0;
        __syncthreads();
        s[t] += v;
        __syncthreads();
    }
    if (t < NB) bsx[t] = s[t] - orig;   // exclusive
}

__global__ void scan_final_kernel(const int* __restrict__ deg, const int* __restrict__ bsx,
                                  int* __restrict__ row_ptr, int* __restrict__ rfill, int N_) {
    __shared__ int s[256];
    int t = threadIdx.x;
    int i = blockIdx.x * 256 + t;
    int orig = (i < N_) ? deg[i] : 0;
    s[t] = orig;
    __syncthreads();
    for (int off = 1; off < 256; off <<= 1) {
        int v = (t >= off) ? s[t - off] : 0;
        __syncthreads();
        s[t] += v;
        __syncthreads();
    }
    int excl = s[t] - orig + bsx[blockIdx.x];
    if (i < N_) { row_ptr[i] = excl; rfill[i] = excl; }
    if (i == N_ - 1) row_ptr[N_] = excl + orig;  // = E
}

__global__ void dinv_kernel(const int* __restrict__ deg, float* __restrict__ dinv, int N_) {
    int i = blockIdx.x * blockDim.x + threadIdx.x;
    if (i < N_) dinv[i] = 1.0f / sqrtf((float)(deg[i] + 1));  // +1 self-loop; always > 0
}

__global__ void fill_kernel(const int* __restrict__ src, const int* __restrict__ dst,
                            int* __restrict__ cur, int* __restrict__ col_src, int E_) {
    int i = blockIdx.x * blockDim.x + threadIdx.x;
    if (i < E_) {
        int p = atomicAdd(&cur[dst[i]], 1);
        col_src[p] = src[i];
    }
}

// ---------------- helpers ----------------

__device__ __forceinline__ ushort f2bf(float f) {  // RNE f32 -> bf16
    uint u = __float_as_uint(f);
    u += 0x7fffu + ((u >> 16) & 1u);
    return (ushort)(u >> 16);
}

__device__ __forceinline__ void bf2x(uint u, float& a, float& b) {
    a = __uint_as_float((u & 0x0000ffffu) << 16);
    b = __uint_as_float(u & 0xffff0000u);
}

// ---------------- GEMM: Mbf16[r][c] = bf16( dinv[r] * sum_k in[r][k] * W[k][c] ) ----------------

__global__ __launch_bounds__(256) void gemm_scale_kernel(
    const float* __restrict__ in, const float* __restrict__ W,
    const float* __restrict__ dinv, ushort* __restrict__ outbf, int N_)
{
    __shared__ float hl[64][F_DIM];   // 32 KB, k-index XOR-swizzled per row
    __shared__ float Wl[F_DIM][64];   // 32 KB
    const int tid = threadIdx.x;
    const int brow = (blockIdx.x >> 1) * 64;
    const int bcol = (blockIdx.x & 1) * 64;

    #pragma unroll
    for (int i = 0; i < 8; ++i) {
        int chunk = tid + i * 256;
        int r = chunk >> 5;        // 0..63
        int k4 = chunk & 31;       // 0..31
        int row = brow + r;
        float4 g = make_float4(0.f, 0.f, 0.f, 0.f);
        if (row < N_) g = *reinterpret_cast<const float4*>(&in[(size_t)row * F_DIM + k4 * 4]);
        int sw = (r & 7) << 2;
        *reinterpret_cast<float4*>(&hl[r][(k4 * 4) ^ sw]) = g;
    }
    #pragma unroll
    for (int i = 0; i < 8; ++i) {
        int chunk = tid + i * 256;
        int k = chunk >> 4;        // 0..127
        int c4 = chunk & 15;       // 0..15
        *reinterpret_cast<float4*>(&Wl[k][c4 * 4]) =
            *reinterpret_cast<const float4*>(&W[(size_t)k * F_DIM + bcol + c4 * 4]);
    }
    __syncthreads();

    const int cg = tid & 15;
    const int rg = tid >> 4;
    const int r0 = rg * 4;
    float acc[4][4] = {};

    #pragma unroll 4
    for (int kk = 0; kk < 32; ++kk) {
        float4 a[4], b[4];
        #pragma unroll
        for (int i = 0; i < 4; ++i) {
            int r = r0 + i;
            int sw = (r & 7) << 2;
            a[i] = *reinterpret_cast<const float4*>(&hl[r][(kk * 4) ^ sw]);
        }
        #pragma unroll
        for (int j = 0; j < 4; ++j)
            b[j] = *reinterpret_cast<const float4*>(&Wl[kk * 4 + j][cg * 4]);
        #pragma unroll
        for (int i = 0; i < 4; ++i) {
            float4 ai = a[i];
            acc[i][0] += ai.x * b[0].x + ai.y * b[1].x + ai.z * b[2].x + ai.w * b[3].x;
            acc[i][1] += ai.x * b[0].y + ai.y * b[1].y + ai.z * b[2].y + ai.w * b[3].y;
            acc[i][2] += ai.x * b[0].z + ai.y * b[1].z + ai.z * b[2].z + ai.w * b[3].z;
            acc[i][3] += ai.x * b[0].w + ai.y * b[1].w + ai.z * b[2].w + ai.w * b[3].w;
        }
    }

    #pragma unroll
    for (int i = 0; i < 4; ++i) {
        int row = brow + r0 + i;
        if (row < N_) {
            float s = dinv[row];
            ushort4 o;
            o.x = f2bf(s * acc[i][0]);
            o.y = f2bf(s * acc[i][1]);
            o.z = f2bf(s * acc[i][2]);
            o.w = f2bf(s * acc[i][3]);
            *reinterpret_cast<ushort4*>(&outbf[(size_t)row * F_DIM + bcol + cg * 4]) = o;
        }
    }
}

// ---------------- Gather-aggregate + bias + relu (bf16 messages) ----------------
// One wave per node (4/block); lane covers features 2*lane, 2*lane+1 (one dword per row).

__global__ __launch_bounds__(256) void gather_kernel(
    const ushort* __restrict__ Mbf, const int* __restrict__ row_ptr,
    const int* __restrict__ col_src, const float* __restrict__ dinv,
    const float* __restrict__ bias, float* __restrict__ Hout, int N_)
{
    int v = blockIdx.x * 4 + (threadIdx.x >> 6);
    if (v >= N_) return;
    int lane = threadIdx.x & 63;
    const uint* M1 = reinterpret_cast<const uint*>(Mbf);   // 2 bf16 per uint, row stride 64
    float accx, accy;
    { float a, b; bf2x(M1[(size_t)v * 64 + lane], a, b); accx = a; accy = b; }  // self loop
    int lo = row_ptr[v], hi = row_ptr[v + 1];
    int e = lo;
    for (; e + 8 <= hi; e += 8) {
        int s0 = col_src[e + 0], s1 = col_src[e + 1], s2 = col_src[e + 2], s3 = col_src[e + 3];
        int s4 = col_src[e + 4], s5 = col_src[e + 5], s6 = col_src[e + 6], s7 = col_src[e + 7];
        uint u0 = M1[(size_t)s0 * 64 + lane];
        uint u1 = M1[(size_t)s1 * 64 + lane];
        uint u2 = M1[(size_t)s2 * 64 + lane];
        uint u3 = M1[(size_t)s3 * 64 + lane];
        uint u4 = M1[(size_t)s4 * 64 + lane];
        uint u5 = M1[(size_t)s5 * 64 + lane];
        uint u6 = M1[(size_t)s6 * 64 + lane];
        uint u7 = M1[(size_t)s7 * 64 + lane];
        float a, b;
        bf2x(u0, a, b); accx += a; accy += b;
        bf2x(u1, a, b); accx += a; accy += b;
        bf2x(u2, a, b); accx += a; accy += b;
        bf2x(u3, a, b); accx += a; accy += b;
        bf2x(u4, a, b); accx += a; accy += b;
        bf2x(u5, a, b); accx += a; accy += b;
        bf2x(u6, a, b); accx += a; accy += b;
        bf2x(u7, a, b); accx += a; accy += b;
    }
    for (; e < hi; ++e) {
        float a, b; bf2x(M1[(size_t)col_src[e] * 64 + lane], a, b);
        accx += a; accy += b;
    }
    float dv = dinv[v];
    float2 bb = reinterpret_cast<const float2*>(bias)[lane];
    float2 o;
    o.x = fmaxf(dv * accx + bb.x, 0.0f);
    o.y = fmaxf(dv * accy + bb.y, 0.0f);
    reinterpret_cast<float2*>(Hout)[(size_t)v * 64 + lane] = o;
}

// ---------------- Mean-pool per graph + final linear (two-stage, deterministic) ----------------

__device__ __forceinline__ int lower_bound_i(const int* __restrict__ a, int n, int key) {
    int lo = 0, hi = n;
    while (lo < hi) {
        int mid = (lo + hi) >> 1;
        if (a[mid] < key) lo = mid + 1; else hi = mid;
    }
    return lo;
}

__global__ __launch_bounds__(128) void pool_part_kernel(
    const float* __restrict__ H, const int* __restrict__ batch,
    float* __restrict__ partial, int N_)
{
    int g = blockIdx.x / POOL_SEG;
    int s = blockIdx.x % POOL_SEG;
    int lo = lower_bound_i(batch, N_, g);
    int hi = lower_bound_i(batch, N_, g + 1);
    int len = hi - lo;
    int chunk = (len + POOL_SEG - 1) / POOL_SEG;
    int a = lo + s * chunk;
    int b = min(a + chunk, hi);
    int col = threadIdx.x;
    float acc = 0.f;
    for (int n = a; n < b; ++n) acc += H[(size_t)n * F_DIM + col];
    partial[((size_t)g * POOL_SEG + s) * F_DIM + col] = acc;
}

__global__ __launch_bounds__(128) void pool_final_kernel(
    const float* __restrict__ partial, const int* __restrict__ batch,
    const float* __restrict__ lin_w, const float* __restrict__ lin_b,
    float* __restrict__ out, int N_)
{
    int g = blockIdx.x;
    int col = threadIdx.x;
    float acc = 0.f;
    #pragma unroll
    for (int s = 0; s < POOL_SEG; ++s)
        acc += partial[((size_t)g * POOL_SEG + s) * F_DIM + col];
    int lo = lower_bound_i(batch, N_, g);
    int hi = lower_bound_i(batch, N_, g + 1);
    float pooled = acc / fmaxf((float)(hi - lo), 1.0f);
    float v = pooled * lin_w[col];
    __shared__ float sm[128];
    sm[col] = v;
    __syncthreads();
    if (col < 64) {
        float t = sm[col] + sm[col + 64];
        for (int off = 32; off; off >>= 1) t += __shfl_down(t, off);
        if (col == 0) out[g] = t + lin_b[0];
    }
}

// ---------------- Launch ----------------

extern "C" void kernel_launch(void* const* d_in, const int* in_sizes, int n_in,
                              void* d_out, int out_size, void* d_ws, size_t ws_size,
                              hipStream_t stream) {
    const float* x     = (const float*)d_in[0];
    const int*   ei    = (const int*)d_in[1];
    const int*   batch = (const int*)d_in[2];
    const float* W0    = (const float*)d_in[3];
    const float* b0    = (const float*)d_in[4];
    const float* W1    = (const float*)d_in[5];
    const float* b1    = (const float*)d_in[6];
    const float* W2    = (const float*)d_in[7];
    const float* b2    = (const float*)d_in[8];
    const float* lin_w = (const float*)d_in[9];
    const float* lin_b = (const float*)d_in[10];

    const int N_ = in_sizes[2];
    const int E_ = in_sizes[1] / 2;
    const int G_ = out_size;
    const int* esrc = ei;
    const int* edst = ei + E_;

    // workspace layout (bytes from d_ws)
    char* p = reinterpret_cast<char*>(d_ws);
    ushort* Mbf = reinterpret_cast<ushort*>(p);        p += (size_t)N_ * F_DIM * sizeof(ushort);
    float*  Hbuf = reinterpret_cast<float*>(p);        p += (size_t)N_ * F_DIM * sizeof(float);
    float*  dinvp = reinterpret_cast<float*>(p);       p += (size_t)N_ * sizeof(float);
    int*    deg = reinterpret_cast<int*>(p);           p += (size_t)N_ * sizeof(int);
    int*    row_ptr = reinterpret_cast<int*>(p);       p += (size_t)(N_ + 4) * sizeof(int);
    int*    rfill = reinterpret_cast<int*>(p);         p += (size_t)N_ * sizeof(int);
    int*    col_src = reinterpret_cast<int*>(p);       p += (size_t)E_ * sizeof(int);
    const int NB = (N_ + 255) / 256;
    int*    bsum = reinterpret_cast<int*>(p);          p += (size_t)NB * sizeof(int);
    int*    bsx = reinterpret_cast<int*>(p);
    float*  partial = reinterpret_cast<float*>(d_ws);  // alias Mbf region (dead during pooling)

    hipMemsetAsync(deg, 0, (size_t)N_ * sizeof(int), stream);

    int eb = (E_ + 255) / 256;
    count_kernel<<<eb, 256, 0, stream>>>(edst, deg, E_);
    scan_blocksums_kernel<<<NB, 256, 0, stream>>>(deg, bsum, N_);
    scan_bs_kernel<<<1, 256, 0, stream>>>(bsum, bsx, NB);
    scan_final_kernel<<<NB, 256, 0, stream>>>(deg, bsx, row_ptr, rfill, N_);
    dinv_kernel<<<(N_ + 255) / 256, 256, 0, stream>>>(deg, dinvp, N_);
    fill_kernel<<<eb, 256, 0, stream>>>(esrc, edst, rfill, col_src, E_);

    const int gemm_grid = ((N_ + 63) / 64) * 2;
    const int gat_grid  = (N_ + 3) / 4;

    const float* cur_in = x;
    const float* Ws[3] = {W0, W1, W2};
    const float* bias[3] = {b0, b1, b2};
    for (int l = 0; l < 3; ++l) {
        gemm_scale_kernel<<<gemm_grid, 256, 0, stream>>>(cur_in, Ws[l], dinvp, Mbf, N_);
        gather_kernel<<<gat_grid, 256, 0, stream>>>(Mbf, row_ptr, col_src, dinvp, bias[l], Hbuf, N_);
        cur_in = Hbuf;
    }

    pool_part_kernel<<<G_ * POOL_SEG, 128, 0, stream>>>(Hbuf, batch, partial, N_);
    pool_final_kernel<<<G_, 128, 0, stream>>>(partial, batch, lin_w, lin_b, (float*)d_out, N_);
}